// Round 11
// baseline (1492.808 us; speedup 1.0000x reference)
//
#include <hip/hip_runtime.h>
#include <hip/hip_bf16.h>

#define NSEQ 512
#define SEGS 511     // L-1
#define CIN  32

__device__ __forceinline__ float rl(float v, int lane) {
    return __int_as_float(__builtin_amdgcn_readlane(__float_as_int(v), lane));
}

__device__ __forceinline__ float tanhf_fast(float x) {
    // tanh(x) = sign(x) * (1 - e) / (1 + e),  e = exp(-2|x|)  — no overflow path
    float ax = fabsf(x);
    float e = __expf(-2.0f * ax);
#if __has_builtin(__builtin_amdgcn_rcpf)
    float r = (1.0f - e) * __builtin_amdgcn_rcpf(1.0f + e);
#else
    float r = (1.0f - e) / (1.0f + e);
#endif
    return copysignf(r, x);
}

// r8 structure (best: 1368 us), ONE change: 8-deep readlane batching.
// Theory: the per-stage stall (~900 cyc) is v_readlane->v_fmac SGPR-RAW
// bubbles, pipelined only ~2-deep by the scheduler. Explicit batches of 8
// independent readlanes followed by the 8 FMAs (in the ORIGINAL accumulation
// order -> bit-identical numerics) give an 8-wide window to hide the SGPR
// write latency under issue.
//
// Block = ONE sequence x 2 waves (128 thr), grid = 512; weights register-
// resident (amdgpu_waves_per_eu(1,1) -> 512-VGPR budget, no remat pressure,
// plus opaque pins). mm1 column-split (col = 64w+lane), mm2 K-split with one
// 512B LDS exchange + one __syncthreads per stage (parity double-buffered).
// Occupancy deliberately 1 wave/SIMD (r8 beat r9's 2/SIMD and r5/r6's
// LDS-streaming variants).
__attribute__((amdgpu_waves_per_eu(1, 1)))
__global__ __launch_bounds__(128) void node_kernel(
    const float* __restrict__ cA, const float* __restrict__ cB,
    const float* __restrict__ cC, const float* __restrict__ cD,
    const int*   __restrict__ final_index,
    const float* __restrict__ W_init, const float* __restrict__ b_init,
    const float* __restrict__ W1, const float* __restrict__ b1,
    const float* __restrict__ W2, const float* __restrict__ b2,
    const float* __restrict__ W_out, const float* __restrict__ b_out,
    float* __restrict__ out)
{
    __shared__ float zz[2][2][64];         // [parity][wave][lane] mm2 partials

    const int tid  = threadIdx.x;
    const int lane = tid & 63;
    const int w    = tid >> 6;          // 0..1
    const int b    = blockIdx.x;
    const int ch   = lane & 31;
    const int col  = 64 * w + lane;     // this lane's h column (all distinct)

    // ---- W1 column in registers: w1c[i] = W1[i][col] (coalesced 256B/wave) ----
    float w1c[96];
#pragma unroll
    for (int i = 0; i < 96; ++i) w1c[i] = W1[i * 128 + col];
    // ---- W2 slice: w2c[j] = W2[64w+j][lane] ----
    float w2c[64];
#pragma unroll
    for (int j = 0; j < 64; ++j) w2c[j] = W2[(64 * w + j) * 64 + lane];
    float b1c = b1[col];
    float b2m = b2[lane];

    // pin: results opaque -> cannot be rematerialized from memory in the loop
#pragma unroll
    for (int i = 0; i < 96; ++i) asm volatile("" : "+v"(w1c[i]));
#pragma unroll
    for (int j = 0; j < 64; ++j) asm volatile("" : "+v"(w2c[j]));
    asm volatile("" : "+v"(b1c));
    asm volatile("" : "+v"(b2m));

    const float* a_ptr = cA + (size_t)b * SEGS * CIN;
    const float* bp    = cB + (size_t)b * SEGS * CIN;
    const float* cp    = cC + (size_t)b * SEGS * CIN;
    const float* dp    = cD + (size_t)b * SEGS * CIN;

    // ---- z0 = X(0) @ W_init + b_init  (replicated identically in both waves) ----
    float z = b_init[lane];
    {
        float a0 = a_ptr[ch];
#pragma unroll
        for (int i = 0; i < 32; ++i)
            z = fmaf(rl(a0, i), W_init[i * 64 + lane], z);
    }

    const int fi = final_index[b];      // ONE seq per block: tight loop bound

    // current-segment coeffs (lanes 0..31 meaningful; per-wave copy)
    float acur = a_ptr[ch], bcur = bp[ch], ccur = cp[ch], dcur = dp[ch];
    float k1 = 0.f, k2 = 0.f, k3 = 0.f, k4 = 0.f;

    __syncthreads();

// 8 independent readlanes, then the 8 FMAs in original accumulation order.
#define B8_W1(SRC, SL, WB) do {                                              \
    float u0 = rl((SRC), (SL) + 0), u1 = rl((SRC), (SL) + 1);                \
    float u2 = rl((SRC), (SL) + 2), u3 = rl((SRC), (SL) + 3);                \
    float u4 = rl((SRC), (SL) + 4), u5 = rl((SRC), (SL) + 5);                \
    float u6 = rl((SRC), (SL) + 6), u7 = rl((SRC), (SL) + 7);                \
    h0 = fmaf(u0, w1c[(WB) + 0], h0); h1 = fmaf(u1, w1c[(WB) + 1], h1);      \
    h0 = fmaf(u2, w1c[(WB) + 2], h0); h1 = fmaf(u3, w1c[(WB) + 3], h1);      \
    h0 = fmaf(u4, w1c[(WB) + 4], h0); h1 = fmaf(u5, w1c[(WB) + 5], h1);      \
    h0 = fmaf(u6, w1c[(WB) + 6], h0); h1 = fmaf(u7, w1c[(WB) + 7], h1);      \
} while (0)

#define B8_W2(HV, JB) do {                                                   \
    float v0 = rl((HV), (JB) + 0), v1 = rl((HV), (JB) + 1);                  \
    float v2 = rl((HV), (JB) + 2), v3 = rl((HV), (JB) + 3);                  \
    float v4 = rl((HV), (JB) + 4), v5 = rl((HV), (JB) + 5);                  \
    float v6 = rl((HV), (JB) + 6), v7 = rl((HV), (JB) + 7);                  \
    zp = fmaf(v0, w2c[(JB) + 0], zp); zq = fmaf(v1, w2c[(JB) + 1], zq);      \
    zp = fmaf(v2, w2c[(JB) + 2], zp); zq = fmaf(v3, w2c[(JB) + 3], zq);      \
    zp = fmaf(v4, w2c[(JB) + 4], zp); zq = fmaf(v5, w2c[(JB) + 5], zq);      \
    zp = fmaf(v6, w2c[(JB) + 6], zp); zq = fmaf(v7, w2c[(JB) + 7], zq);      \
} while (0)

#define MM_STAGE(YS, XC, PAR, KOUT) do {                                     \
    float h0 = 0.f, h1 = 0.f;                                                \
    _Pragma("unroll")                                                        \
    for (int i = 0; i < 64; i += 8) B8_W1((YS), i, i);                       \
    _Pragma("unroll")                                                        \
    for (int i = 0; i < 32; i += 8) B8_W1((XC), i, 64 + i);                  \
    float h = tanhf_fast(h0 + h1 + b1c);  /* this lane's col = 64w+lane */   \
    float zp = 0.f, zq = 0.f;                                                \
    _Pragma("unroll")                                                        \
    for (int j = 0; j < 64; j += 8) B8_W2(h, j);                             \
    zz[PAR][w][lane] = zp + zq;                                              \
    __syncthreads();                                                         \
    float zo = zz[PAR][w ^ 1][lane];                                         \
    KOUT = tanhf_fast(zp + zq + zo + b2m);                                   \
} while (0)

    for (int t = 0; t < fi; ++t) {
        // spline points of this step from current-segment coeffs
        float x0  = acur;
        float i13 = fmaf(dcur, 1.0f / 9.0f, 0.5f * ccur);
        float x13 = fmaf(fmaf(i13, 1.0f / 3.0f, bcur), 1.0f / 3.0f, acur);
        float i23 = fmaf(dcur, 2.0f / 9.0f, 0.5f * ccur);
        float x23 = fmaf(fmaf(i23, 2.0f / 3.0f, bcur), 2.0f / 3.0f, acur);
        float xbl = acur + (bcur + (0.5f * ccur + dcur * (1.0f / 3.0f)));

        // next-segment prefetch (first use: stage 3 / next iter top)
        const int tn  = (t + 1 < SEGS) ? (t + 1) : (SEGS - 1);
        const int off = tn * CIN + ch;
        float anx = a_ptr[off];
        float bnx = bp[off];
        float cnx = cp[off];
        float dnx = dp[off];

        MM_STAGE(z, x0, 0, k1);
        float ys1 = fmaf(k1, 1.0f / 3.0f, z);
        MM_STAGE(ys1, x13, 1, k2);
        float ys2 = z + (k2 - k1 * (1.0f / 3.0f));
        MM_STAGE(ys2, x23, 0, k3);
        float xb  = (t < SEGS - 1) ? anx : xbl;
        float ys3 = z + (k1 - k2 + k3);
        MM_STAGE(ys3, xb, 1, k4);

        z += (k1 + 3.0f * (k2 + k3) + k4) * 0.125f;
        acur = anx; bcur = bnx; ccur = cnx; dcur = dnx;
    }

    // ---- out[b] = z_fi @ W_out + b_out ----
    if (w == 0 && lane < 10) {
        float acc = b_out[lane];
#pragma unroll
        for (int m = 0; m < 64; ++m)
            acc = fmaf(rl(z, m), W_out[m * 10 + lane], acc);
        out[b * 10 + lane] = acc;
    }
}

extern "C" void kernel_launch(void* const* d_in, const int* in_sizes, int n_in,
                              void* d_out, int out_size, void* d_ws, size_t ws_size,
                              hipStream_t stream) {
    const float* cA     = (const float*)d_in[1];
    const float* cBc    = (const float*)d_in[2];
    const float* cCc    = (const float*)d_in[3];
    const float* cDc    = (const float*)d_in[4];
    const int*   fidx   = (const int*)d_in[5];
    const float* W_init = (const float*)d_in[6];
    const float* b_init = (const float*)d_in[7];
    const float* W1     = (const float*)d_in[8];
    const float* b1     = (const float*)d_in[9];
    const float* W2     = (const float*)d_in[10];
    const float* b2     = (const float*)d_in[11];
    const float* W_out  = (const float*)d_in[12];
    const float* b_out  = (const float*)d_in[13];

    node_kernel<<<dim3(NSEQ), dim3(128), 0, stream>>>(
        cA, cBc, cCc, cDc, fidx, W_init, b_init, W1, b1, W2, b2, W_out, b_out,
        (float*)d_out);
}

// Round 12
// 1427.067 us; speedup vs baseline: 1.0461x; 1.0461x over previous
//
#include <hip/hip_runtime.h>
#include <hip/hip_bf16.h>

#define NSEQ 512
#define SEGS 511     // L-1
#define CIN  32

__device__ __forceinline__ float rl(float v, int lane) {
    return __int_as_float(__builtin_amdgcn_readlane(__float_as_int(v), lane));
}

__device__ __forceinline__ float tanhf_fast(float x) {
    // tanh(x) = sign(x) * (1 - e) / (1 + e),  e = exp(-2|x|)  — no overflow path
    float ax = fabsf(x);
    float e = __expf(-2.0f * ax);
#if __has_builtin(__builtin_amdgcn_rcpf)
    float r = (1.0f - e) * __builtin_amdgcn_rcpf(1.0f + e);
#else
    float r = (1.0f - e) / (1.0f + e);
#endif
    return copysignf(r, x);
}

// r12: r8 skeleton (2 waves/seq, col-split mm1, K-split mm2, 1 barrier/stage,
// weights register-resident via amdgpu_waves_per_eu(1,1) + opaque pins), with
// the mm1 LINEARITY DECOMPOSITION:
//   mm1(ys_s)[col] = Z[col] + XP_s[col] + combo_s(K1,K2,K3)[col]
// where Z = sum_i z_i W1[i][col] (z fixed within a step -> once per step),
// XP_s = spline-input part (k-independent -> step-top, fills latency bubbles),
// K_n = sum_i k_n,i W1[i][col] (the only k-dependent broadcast, 64 pairs).
// RK-3/8: stage1 = Z+XP0; stage2 = +K1/3; stage3 = +K2-K1/3; stage4 = +K1-K2+K3.
// Total instruction count is UNCHANGED; the serial k-chain loses ~1/3 of its
// instructions (issue-bound regime: clock inferred ~1.45 GHz from VALUBusy,
// r8 wall ~= issue + ~300cyc latency/stage).
__attribute__((amdgpu_waves_per_eu(1, 1)))
__global__ __launch_bounds__(128) void node_kernel(
    const float* __restrict__ cA, const float* __restrict__ cB,
    const float* __restrict__ cC, const float* __restrict__ cD,
    const int*   __restrict__ final_index,
    const float* __restrict__ W_init, const float* __restrict__ b_init,
    const float* __restrict__ W1, const float* __restrict__ b1,
    const float* __restrict__ W2, const float* __restrict__ b2,
    const float* __restrict__ W_out, const float* __restrict__ b_out,
    float* __restrict__ out)
{
    __shared__ float zz[2][2][64];         // [parity][wave][lane] mm2 partials

    const int tid  = threadIdx.x;
    const int lane = tid & 63;
    const int w    = tid >> 6;          // 0..1
    const int b    = blockIdx.x;
    const int ch   = lane & 31;
    const int col  = 64 * w + lane;     // this lane's h column (all distinct)

    // ---- W1 column in registers: w1c[i] = W1[i][col] ----
    float w1c[96];
#pragma unroll
    for (int i = 0; i < 96; ++i) w1c[i] = W1[i * 128 + col];
    // ---- W2 slice: w2c[j] = W2[64w+j][lane] ----
    float w2c[64];
#pragma unroll
    for (int j = 0; j < 64; ++j) w2c[j] = W2[(64 * w + j) * 64 + lane];
    float b1c = b1[col];
    float b2m = b2[lane];

    // pin: opaque -> cannot be rematerialized from memory inside the loop
#pragma unroll
    for (int i = 0; i < 96; ++i) asm volatile("" : "+v"(w1c[i]));
#pragma unroll
    for (int j = 0; j < 64; ++j) asm volatile("" : "+v"(w2c[j]));
    asm volatile("" : "+v"(b1c));
    asm volatile("" : "+v"(b2m));

    const float* a_ptr = cA + (size_t)b * SEGS * CIN;
    const float* bp    = cB + (size_t)b * SEGS * CIN;
    const float* cp    = cC + (size_t)b * SEGS * CIN;
    const float* dp    = cD + (size_t)b * SEGS * CIN;

    // ---- z0 = X(0) @ W_init + b_init  (replicated identically in both waves) ----
    float z = b_init[lane];
    {
        float a0 = a_ptr[ch];
#pragma unroll
        for (int i = 0; i < 32; ++i)
            z = fmaf(rl(a0, i), W_init[i * 64 + lane], z);
    }

    const int fi = final_index[b];

    // current-segment coeffs (lanes 0..31 meaningful; per-wave copy)
    float acur = a_ptr[ch], bcur = bp[ch], ccur = cp[ch], dcur = dp[ch];
    float k1 = 0.f, k2 = 0.f, k3 = 0.f, k4 = 0.f;

    __syncthreads();

// 64-wide broadcast accumulate into two chains over w1c[WB..WB+63]
#define BC64(SRC, AA, BB) do {                                               \
    _Pragma("unroll")                                                        \
    for (int i = 0; i < 64; i += 2) {                                        \
        float u0 = rl((SRC), i), u1 = rl((SRC), i + 1);                      \
        AA = fmaf(u0, w1c[i], AA);                                           \
        BB = fmaf(u1, w1c[i + 1], BB);                                       \
    }                                                                        \
} while (0)

// 32-wide broadcast accumulate over the X rows w1c[64..95]
#define BC32X(SRC, AA, BB) do {                                              \
    _Pragma("unroll")                                                        \
    for (int i = 0; i < 32; i += 2) {                                        \
        float u0 = rl((SRC), i), u1 = rl((SRC), i + 1);                      \
        AA = fmaf(u0, w1c[64 + i], AA);                                      \
        BB = fmaf(u1, w1c[64 + i + 1], BB);                                  \
    }                                                                        \
} while (0)

// mm2 + exchange + k-tanh (unchanged from r8)
#define MM2_STAGE(H, PAR, KOUT) do {                                         \
    float zp = 0.f, zq = 0.f;                                                \
    _Pragma("unroll")                                                        \
    for (int j = 0; j < 64; j += 2) {                                        \
        zp = fmaf(rl((H), j),     w2c[j],     zp);                           \
        zq = fmaf(rl((H), j + 1), w2c[j + 1], zq);                           \
    }                                                                        \
    zz[PAR][w][lane] = zp + zq;                                              \
    __syncthreads();                                                         \
    float zo = zz[PAR][w ^ 1][lane];                                         \
    KOUT = tanhf_fast(zp + zq + zo + b2m);                                   \
} while (0)

    for (int t = 0; t < fi; ++t) {
        // ---- step-top, k-independent ----
        float i13 = fmaf(dcur, 1.0f / 9.0f, 0.5f * ccur);
        float x13 = fmaf(fmaf(i13, 1.0f / 3.0f, bcur), 1.0f / 3.0f, acur);
        float i23 = fmaf(dcur, 2.0f / 9.0f, 0.5f * ccur);
        float x23 = fmaf(fmaf(i23, 2.0f / 3.0f, bcur), 2.0f / 3.0f, acur);
        float xbl = acur + (bcur + (0.5f * ccur + dcur * (1.0f / 3.0f)));

        // next-segment prefetch (xb consumer sits after stage 1)
        const int tn  = (t + 1 < SEGS) ? (t + 1) : (SEGS - 1);
        const int off = tn * CIN + ch;
        float anx = a_ptr[off];
        float bnx = bp[off];
        float cnx = cp[off];
        float dnx = dp[off];

        // Z-part (z fixed for the whole step) and X-parts for stages 0..2
        float Za = 0.f, Zb = 0.f;
        BC64(z, Za, Zb);
        float Zs = Za + Zb + b1c;
        float X0a = 0.f, X0b = 0.f; BC32X(acur, X0a, X0b);
        float X1a = 0.f, X1b = 0.f; BC32X(x13,  X1a, X1b);
        float X2a = 0.f, X2b = 0.f; BC32X(x23,  X2a, X2b);
        float hb0 = Zs + (X0a + X0b);
        float hb1 = Zs + (X1a + X1b);
        float hb2 = Zs + (X2a + X2b);

        // ---- stage 1: ys = z -> mm1 fully precomputed ----
        float h1v = tanhf_fast(hb0);
        MM2_STAGE(h1v, 0, k1);

        // K1 broadcast (needed by stages 2,3,4)
        float K1a = 0.f, K1b = 0.f;
        BC64(k1, K1a, K1b);
        float K1 = K1a + K1b;

        // XP3 here: prefetch latency covered by step-top + stage 1
        float xb = (t < SEGS - 1) ? anx : xbl;
        float X3a = 0.f, X3b = 0.f; BC32X(xb, X3a, X3b);
        float hb3 = Zs + (X3a + X3b);

        // ---- stage 2: ys = z + k1/3 ----
        float h2v = tanhf_fast(fmaf(K1, 1.0f / 3.0f, hb1));
        MM2_STAGE(h2v, 1, k2);

        float K2a = 0.f, K2b = 0.f;
        BC64(k2, K2a, K2b);
        float K2 = K2a + K2b;

        // ---- stage 3: ys = z + (k2 - k1/3) ----
        float h3v = tanhf_fast(hb2 + (K2 - K1 * (1.0f / 3.0f)));
        MM2_STAGE(h3v, 0, k3);

        float K3a = 0.f, K3b = 0.f;
        BC64(k3, K3a, K3b);
        float K3 = K3a + K3b;

        // ---- stage 4: ys = z + (k1 - k2 + k3) ----
        float h4v = tanhf_fast(hb3 + ((K1 - K2) + K3));
        MM2_STAGE(h4v, 1, k4);

        z += (k1 + 3.0f * (k2 + k3) + k4) * 0.125f;
        acur = anx; bcur = bnx; ccur = cnx; dcur = dnx;
    }

    // ---- out[b] = z_fi @ W_out + b_out ----
    if (w == 0 && lane < 10) {
        float acc = b_out[lane];
#pragma unroll
        for (int m = 0; m < 64; ++m)
            acc = fmaf(rl(z, m), W_out[m * 10 + lane], acc);
        out[b * 10 + lane] = acc;
    }
}

extern "C" void kernel_launch(void* const* d_in, const int* in_sizes, int n_in,
                              void* d_out, int out_size, void* d_ws, size_t ws_size,
                              hipStream_t stream) {
    const float* cA     = (const float*)d_in[1];
    const float* cBc    = (const float*)d_in[2];
    const float* cCc    = (const float*)d_in[3];
    const float* cDc    = (const float*)d_in[4];
    const int*   fidx   = (const int*)d_in[5];
    const float* W_init = (const float*)d_in[6];
    const float* b_init = (const float*)d_in[7];
    const float* W1     = (const float*)d_in[8];
    const float* b1     = (const float*)d_in[9];
    const float* W2     = (const float*)d_in[10];
    const float* b2     = (const float*)d_in[11];
    const float* W_out  = (const float*)d_in[12];
    const float* b_out  = (const float*)d_in[13];

    node_kernel<<<dim3(NSEQ), dim3(128), 0, stream>>>(
        cA, cBc, cCc, cDc, fidx, W_init, b_init, W1, b1, W2, b2, W_out, b_out,
        (float*)d_out);
}